// Round 5
// baseline (409.504 us; speedup 1.0000x reference)
//
#include <hip/hip_runtime.h>
#include <hip/hip_cooperative_groups.h>
#include <math.h>

namespace cg = cooperative_groups;

// Problem constants (from reference setup)
constexpr int B  = 32;
constexpr int C  = 64;
constexpr int H  = 128;
constexpr int W  = 128;
constexpr int HW = H * W;            // 16384
constexpr int SB = 2 * C * HW;       // per-batch stride in floats
constexpr float EPS = 1e-5f;

constexpr int NTHR  = 256;
constexpr int PAIRS = 2;             // plane-pairs per block
constexpr int NBLK  = (B * C) / PAIRS;   // 1024
constexpr int NIT   = HW / (NTHR * 4);   // 16 float4-iterations per plane

typedef float v4f __attribute__((ext_vector_type(4)));

struct Coefs { float mr, mi, a00, a01, a10, a11, b0, b1; };

// ---------------------------------------------------------------------------
// Per-channel whitening coefficients from the 32 per-batch partials.
// Reference math implemented LITERALLY (t = sqrt(tau + 2*delta); s added to
// all four q entries).
// ---------------------------------------------------------------------------
__device__ __forceinline__ Coefs channel_coefs(const float* __restrict__ part,
                                               const float* __restrict__ gamma,
                                               const float* __restrict__ beta,
                                               int c) {
    float sr = 0.f, si = 0.f, srr = 0.f, sii = 0.f, sri = 0.f;
    const float* p = part + (size_t)c * B * 5;
#pragma unroll
    for (int b = 0; b < B; ++b) {
        sr  += p[b * 5 + 0];
        si  += p[b * 5 + 1];
        srr += p[b * 5 + 2];
        sii += p[b * 5 + 3];
        sri += p[b * 5 + 4];
    }
    const float N    = (float)(B * HW);
    const float invN = 1.f / N;
    Coefs o;
    o.mr = sr * invN;
    o.mi = si * invN;
    const float d = N - 1.f;

    const float covRR = (srr - N * o.mr * o.mr) / d;
    const float covII = (sii - N * o.mi * o.mi) / d;
    const float covRI = (sri - N * o.mr * o.mi) / d;

    const float m00 = covRR + EPS;
    const float m01 = covRI;
    const float m10 = covRI;
    const float m11 = covII + EPS;

    const float tau   = m00 + m11;
    const float delta = m00 * m11 - m01 * m10;
    const float s     = sqrtf(delta);
    const float t     = sqrtf(tau + 2.f * delta);   // reference: delta, not s

    const float q00 = (m00 + s) / t;
    const float q01 = (m01 + s) / t;
    const float q10 = (m10 + s) / t;
    const float q11 = (m11 + s) / t;

    const float det    = q00 * q11 - q01 * q10;
    const float invdet = 1.f / det;
    const float v00 =  q11 * invdet;
    const float v01 = -q01 * invdet;
    const float v10 = -q10 * invdet;
    const float v11 =  q00 * invdet;

    const float g00 = gamma[c * 4 + 0];
    const float g01 = gamma[c * 4 + 1];
    const float g10 = gamma[c * 4 + 2];
    const float g11 = gamma[c * 4 + 3];

    o.a00 = g00 * v00 + g01 * v10;
    o.a01 = g00 * v01 + g01 * v11;
    o.a10 = g10 * v00 + g11 * v10;
    o.a11 = g10 * v01 + g11 * v11;
    o.b0  = beta[c * 2 + 0];
    o.b1  = beta[c * 2 + 1];
    return o;
}

__device__ __forceinline__ void accum(const v4f r, const v4f i,
                                      float& sr, float& si,
                                      float& srr, float& sii, float& sri) {
    sr  += r.x + r.y + r.z + r.w;
    si  += i.x + i.y + i.z + i.w;
    srr += r.x * r.x + r.y * r.y + r.z * r.z + r.w * r.w;
    sii += i.x * i.x + i.y * i.y + i.z * i.z + i.w * i.w;
    sri += r.x * i.x + r.y * i.y + r.z * i.z + r.w * i.w;
}

__device__ __forceinline__ void reduce_and_store(float sr, float si, float srr,
                                                 float sii, float sri,
                                                 float (*red)[5],
                                                 float* __restrict__ part,
                                                 int c, int b) {
#pragma unroll
    for (int off = 32; off > 0; off >>= 1) {
        sr  += __shfl_down(sr,  off);
        si  += __shfl_down(si,  off);
        srr += __shfl_down(srr, off);
        sii += __shfl_down(sii, off);
        sri += __shfl_down(sri, off);
    }
    const int tid  = threadIdx.x;
    const int wave = tid >> 6;
    if ((tid & 63) == 0) {
        red[wave][0] = sr;  red[wave][1] = si;  red[wave][2] = srr;
        red[wave][3] = sii; red[wave][4] = sri;
    }
    __syncthreads();
    if (tid == 0) {
        float* dst = part + ((size_t)c * B + b) * 5;
#pragma unroll
        for (int k = 0; k < 5; ++k)
            dst[k] = red[0][k] + red[1][k] + red[2][k] + red[3][k];
    }
    __syncthreads();
}

__device__ __forceinline__ v4f whitenR(const v4f r, const v4f i, const Coefs& k) {
    v4f y;
    y.x = k.a00 * (r.x - k.mr) + k.a01 * (i.x - k.mi) + k.b0;
    y.y = k.a00 * (r.y - k.mr) + k.a01 * (i.y - k.mi) + k.b0;
    y.z = k.a00 * (r.z - k.mr) + k.a01 * (i.z - k.mi) + k.b0;
    y.w = k.a00 * (r.w - k.mr) + k.a01 * (i.w - k.mi) + k.b0;
    return y;
}
__device__ __forceinline__ v4f whitenI(const v4f r, const v4f i, const Coefs& k) {
    v4f y;
    y.x = k.a10 * (r.x - k.mr) + k.a11 * (i.x - k.mi) + k.b1;
    y.y = k.a10 * (r.y - k.mr) + k.a11 * (i.y - k.mi) + k.b1;
    y.z = k.a10 * (r.z - k.mr) + k.a11 * (i.z - k.mi) + k.b1;
    y.w = k.a10 * (r.w - k.mr) + k.a11 * (i.w - k.mi) + k.b1;
    return y;
}

// ---------------------------------------------------------------------------
// Fused cooperative kernel, NO retention: rely on L2+L3 residency for the
// second read (proven: replay FETCH ~ 0 in R4). High occupancy is the lever:
// 1024 blocks x 256 thr, tiny LDS, VGPR<=128 -> >=4 blocks/CU co-resident.
// ---------------------------------------------------------------------------
__global__ __launch_bounds__(NTHR, 4) void k_fused(const float* __restrict__ x,
                                                   const float* __restrict__ gamma,
                                                   const float* __restrict__ beta,
                                                   float* __restrict__ part,
                                                   float* __restrict__ out) {
    __shared__ float red[4][5];

    const int tid   = threadIdx.x;
    const int bid   = blockIdx.x;
    const int pair0 = PAIRS * bid;
    const int b     = pair0 >> 6;       // PAIRS divides C
    const int cbase = pair0 & 63;

    // ---------------- pass 1: stats ----------------
#pragma unroll
    for (int p = 0; p < PAIRS; ++p) {
        const float* xr = x + (size_t)b * SB + (size_t)(cbase + p) * HW;
        const float* xi = xr + (size_t)C * HW;
        float sr = 0.f, si = 0.f, srr = 0.f, sii = 0.f, sri = 0.f;
#pragma unroll
        for (int it = 0; it < NIT; ++it) {
            const int idx = (it * NTHR + tid) * 4;
            const v4f r = *reinterpret_cast<const v4f*>(xr + idx);
            const v4f i = *reinterpret_cast<const v4f*>(xi + idx);
            accum(r, i, sr, si, srr, sii, sri);
        }
        reduce_and_store(sr, si, srr, sii, sri, red, part, cbase + p, b);
    }

    __threadfence();
    cg::this_grid().sync();

    // ---------------- pass 2: normalize ----------------
#pragma unroll
    for (int p = 0; p < PAIRS; ++p) {
        const Coefs k = channel_coefs(part, gamma, beta, cbase + p);
        const float* xr = x + (size_t)b * SB + (size_t)(cbase + p) * HW;
        const float* xi = xr + (size_t)C * HW;
        float* orp = out + (size_t)b * SB + (size_t)(cbase + p) * HW;
        float* oip = orp + (size_t)C * HW;
#pragma unroll
        for (int it = 0; it < NIT; ++it) {
            const int idx = (it * NTHR + tid) * 4;
            const v4f r = __builtin_nontemporal_load(reinterpret_cast<const v4f*>(xr + idx));
            const v4f i = __builtin_nontemporal_load(reinterpret_cast<const v4f*>(xi + idx));
            __builtin_nontemporal_store(whitenR(r, i, k), reinterpret_cast<v4f*>(orp + idx));
            __builtin_nontemporal_store(whitenI(r, i, k), reinterpret_cast<v4f*>(oip + idx));
        }
    }
}

// ---------------------------------------------------------------------------
// Fallback pipeline (proven R2 path): partial sums + normalize.
// ---------------------------------------------------------------------------
__global__ __launch_bounds__(256) void k_partial(const float* __restrict__ x,
                                                 float* __restrict__ part) {
    const int c = blockIdx.x;
    const int b = blockIdx.y;
    const float* __restrict__ pxr = x + (size_t)b * SB + (size_t)c * HW;
    const float* __restrict__ pxi = pxr + (size_t)C * HW;
    const int tid = threadIdx.x;

    float sr = 0.f, si = 0.f, srr = 0.f, sii = 0.f, sri = 0.f;
#pragma unroll
    for (int it = 0; it < NIT; ++it) {
        const int idx = (it * 256 + tid) * 4;
        const v4f r = *reinterpret_cast<const v4f*>(pxr + idx);
        const v4f i = *reinterpret_cast<const v4f*>(pxi + idx);
        accum(r, i, sr, si, srr, sii, sri);
    }
    __shared__ float red[4][5];
    reduce_and_store(sr, si, srr, sii, sri, red, part, c, b);
}

__global__ __launch_bounds__(256) void k_norm(const float* __restrict__ x,
                                              const float* __restrict__ part,
                                              const float* __restrict__ gamma,
                                              const float* __restrict__ beta,
                                              float* __restrict__ out) {
    const int bc = blockIdx.y;
    const int b  = bc / C;
    const int c  = bc % C;
    const Coefs k = channel_coefs(part, gamma, beta, c);

    const size_t baseR = (size_t)b * SB + (size_t)c * HW;
    const size_t baseI = baseR + (size_t)C * HW;
    const int idx = (blockIdx.x * 256 + threadIdx.x) * 4;

    const v4f r = __builtin_nontemporal_load(reinterpret_cast<const v4f*>(x + baseR + idx));
    const v4f i = __builtin_nontemporal_load(reinterpret_cast<const v4f*>(x + baseI + idx));
    __builtin_nontemporal_store(whitenR(r, i, k), reinterpret_cast<v4f*>(out + baseR + idx));
    __builtin_nontemporal_store(whitenI(r, i, k), reinterpret_cast<v4f*>(out + baseI + idx));
}

// ---------------------------------------------------------------------------
extern "C" void kernel_launch(void* const* d_in, const int* in_sizes, int n_in,
                              void* d_out, int out_size, void* d_ws, size_t ws_size,
                              hipStream_t stream) {
    const float* x     = (const float*)d_in[0];
    const float* gamma = (const float*)d_in[1];
    const float* beta  = (const float*)d_in[2];
    float* out  = (float*)d_out;
    float* part = (float*)d_ws;           // C*B*5 = 10240 floats

    void* args[] = {(void*)&x, (void*)&gamma, (void*)&beta,
                    (void*)&part, (void*)&out};
    hipError_t err = hipLaunchCooperativeKernel((const void*)k_fused,
                                                dim3(NBLK), dim3(NTHR),
                                                args, 0, stream);
    if (err != hipSuccess) {
        // Cooperative path unavailable: proven two-kernel pipeline.
        k_partial<<<dim3(C, B), 256, 0, stream>>>(x, part);
        k_norm<<<dim3(HW / 1024, B * C), 256, 0, stream>>>(x, part, gamma, beta, out);
    }
}

// Round 6
// 124.073 us; speedup vs baseline: 3.3005x; 3.3005x over previous
//
#include <hip/hip_runtime.h>
#include <math.h>

// Problem constants (from reference setup)
constexpr int B  = 32;
constexpr int C  = 64;
constexpr int H  = 128;
constexpr int W  = 128;
constexpr int HW = H * W;            // 16384
constexpr int SB = 2 * C * HW;       // per-batch stride in floats
constexpr float EPS = 1e-5f;

constexpr int NTHR = 256;
constexpr int NIT  = HW / (NTHR * 4);   // 16 float4-iterations per plane

typedef float v4f __attribute__((ext_vector_type(4)));

struct Coefs { float mr, mi, a00, a01, a10, a11, b0, b1; };

// ---------------------------------------------------------------------------
// Per-channel whitening coefficients from the 32 per-batch partials.
// Reference math implemented LITERALLY (t = sqrt(tau + 2*delta); s added to
// all four q entries).
// ---------------------------------------------------------------------------
__device__ __forceinline__ Coefs channel_coefs(const float* __restrict__ part,
                                               const float* __restrict__ gamma,
                                               const float* __restrict__ beta,
                                               int c) {
    float sr = 0.f, si = 0.f, srr = 0.f, sii = 0.f, sri = 0.f;
    const float* p = part + (size_t)c * B * 5;
#pragma unroll
    for (int b = 0; b < B; ++b) {
        sr  += p[b * 5 + 0];
        si  += p[b * 5 + 1];
        srr += p[b * 5 + 2];
        sii += p[b * 5 + 3];
        sri += p[b * 5 + 4];
    }
    const float N    = (float)(B * HW);
    const float invN = 1.f / N;
    Coefs o;
    o.mr = sr * invN;
    o.mi = si * invN;
    const float d = N - 1.f;

    const float covRR = (srr - N * o.mr * o.mr) / d;
    const float covII = (sii - N * o.mi * o.mi) / d;
    const float covRI = (sri - N * o.mr * o.mi) / d;

    const float m00 = covRR + EPS;
    const float m01 = covRI;
    const float m10 = covRI;
    const float m11 = covII + EPS;

    const float tau   = m00 + m11;
    const float delta = m00 * m11 - m01 * m10;
    const float s     = sqrtf(delta);
    const float t     = sqrtf(tau + 2.f * delta);   // reference: delta, not s

    const float q00 = (m00 + s) / t;
    const float q01 = (m01 + s) / t;
    const float q10 = (m10 + s) / t;
    const float q11 = (m11 + s) / t;

    const float det    = q00 * q11 - q01 * q10;
    const float invdet = 1.f / det;
    const float v00 =  q11 * invdet;
    const float v01 = -q01 * invdet;
    const float v10 = -q10 * invdet;
    const float v11 =  q00 * invdet;

    const float g00 = gamma[c * 4 + 0];
    const float g01 = gamma[c * 4 + 1];
    const float g10 = gamma[c * 4 + 2];
    const float g11 = gamma[c * 4 + 3];

    o.a00 = g00 * v00 + g01 * v10;
    o.a01 = g00 * v01 + g01 * v11;
    o.a10 = g10 * v00 + g11 * v10;
    o.a11 = g10 * v01 + g11 * v11;
    o.b0  = beta[c * 2 + 0];
    o.b1  = beta[c * 2 + 1];
    return o;
}

__device__ __forceinline__ void accum(const v4f r, const v4f i,
                                      float& sr, float& si,
                                      float& srr, float& sii, float& sri) {
    sr  += r.x + r.y + r.z + r.w;
    si  += i.x + i.y + i.z + i.w;
    srr += r.x * r.x + r.y * r.y + r.z * r.z + r.w * r.w;
    sii += i.x * i.x + i.y * i.y + i.z * i.z + i.w * i.w;
    sri += r.x * i.x + r.y * i.y + r.z * i.z + r.w * i.w;
}

// ---------------------------------------------------------------------------
// Kernel 1: per-(channel, batch) partial sums. Grid (C, B) = 2048 blocks,
// all co-resident. Streams each plane FORWARD (idx 0 -> 16K); at kernel end
// the L3 (memory-side) holds x ordered by recency: high offsets freshest.
// ---------------------------------------------------------------------------
__global__ __launch_bounds__(256) void k_partial(const float* __restrict__ x,
                                                 float* __restrict__ part) {
    const int c = blockIdx.x;
    const int b = blockIdx.y;
    const float* __restrict__ pxr = x + (size_t)b * SB + (size_t)c * HW;
    const float* __restrict__ pxi = pxr + (size_t)C * HW;
    const int tid = threadIdx.x;

    float sr = 0.f, si = 0.f, srr = 0.f, sii = 0.f, sri = 0.f;
#pragma unroll
    for (int it = 0; it < NIT; ++it) {
        const int idx = (it * 256 + tid) * 4;
        const v4f r = *reinterpret_cast<const v4f*>(pxr + idx);
        const v4f i = *reinterpret_cast<const v4f*>(pxi + idx);
        accum(r, i, sr, si, srr, sii, sri);
    }

#pragma unroll
    for (int off = 32; off > 0; off >>= 1) {
        sr  += __shfl_down(sr,  off);
        si  += __shfl_down(si,  off);
        srr += __shfl_down(srr, off);
        sii += __shfl_down(sii, off);
        sri += __shfl_down(sri, off);
    }
    __shared__ float red[4][5];
    const int wave = tid >> 6;
    if ((tid & 63) == 0) {
        red[wave][0] = sr;  red[wave][1] = si;  red[wave][2] = srr;
        red[wave][3] = sii; red[wave][4] = sri;
    }
    __syncthreads();
    if (tid == 0) {
        float* dst = part + ((size_t)c * B + b) * 5;
#pragma unroll
        for (int k = 0; k < 5; ++k)
            dst[k] = red[0][k] + red[1][k] + red[2][k] + red[3][k];
    }
}

// ---------------------------------------------------------------------------
// Kernel 2: normalize. 2048 blocks (one per plane-pair), all co-resident.
// Walks each plane BACKWARD (it = NIT-1 -> 0): reads start at the freshest
// L3 data (pass-1 tail) and stay ahead of the write-driven eviction front.
// Regular loads (refresh recency); nt stores (L2 evict-first).
// Steady-state across graph replays: this kernel ends at low offsets, which
// is exactly where the next replay's k_partial begins its forward sweep.
// ---------------------------------------------------------------------------
__global__ __launch_bounds__(256) void k_norm(const float* __restrict__ x,
                                              const float* __restrict__ part,
                                              const float* __restrict__ gamma,
                                              const float* __restrict__ beta,
                                              float* __restrict__ out) {
    const int bc = blockIdx.x;
    const int b  = bc / C;
    const int c  = bc % C;
    const Coefs k = channel_coefs(part, gamma, beta, c);

    const size_t baseR = (size_t)b * SB + (size_t)c * HW;
    const size_t baseI = baseR + (size_t)C * HW;
    const int tid = threadIdx.x;

#pragma unroll
    for (int it = NIT - 1; it >= 0; --it) {
        const int idx = (it * NTHR + tid) * 4;
        const v4f r = *reinterpret_cast<const v4f*>(x + baseR + idx);
        const v4f i = *reinterpret_cast<const v4f*>(x + baseI + idx);

        v4f yr, yi;
        yr.x = k.a00 * (r.x - k.mr) + k.a01 * (i.x - k.mi) + k.b0;
        yr.y = k.a00 * (r.y - k.mr) + k.a01 * (i.y - k.mi) + k.b0;
        yr.z = k.a00 * (r.z - k.mr) + k.a01 * (i.z - k.mi) + k.b0;
        yr.w = k.a00 * (r.w - k.mr) + k.a01 * (i.w - k.mi) + k.b0;
        yi.x = k.a10 * (r.x - k.mr) + k.a11 * (i.x - k.mi) + k.b1;
        yi.y = k.a10 * (r.y - k.mr) + k.a11 * (i.y - k.mi) + k.b1;
        yi.z = k.a10 * (r.z - k.mr) + k.a11 * (i.z - k.mi) + k.b1;
        yi.w = k.a10 * (r.w - k.mr) + k.a11 * (i.w - k.mi) + k.b1;

        __builtin_nontemporal_store(yr, reinterpret_cast<v4f*>(out + baseR + idx));
        __builtin_nontemporal_store(yi, reinterpret_cast<v4f*>(out + baseI + idx));
    }
}

// ---------------------------------------------------------------------------
extern "C" void kernel_launch(void* const* d_in, const int* in_sizes, int n_in,
                              void* d_out, int out_size, void* d_ws, size_t ws_size,
                              hipStream_t stream) {
    const float* x     = (const float*)d_in[0];
    const float* gamma = (const float*)d_in[1];
    const float* beta  = (const float*)d_in[2];
    float* out  = (float*)d_out;
    float* part = (float*)d_ws;           // C*B*5 = 10240 floats

    k_partial<<<dim3(C, B), NTHR, 0, stream>>>(x, part);
    k_norm<<<dim3(B * C), NTHR, 0, stream>>>(x, part, gamma, beta, out);
}